// Round 2
// baseline (730.274 us; speedup 1.0000x reference)
//
#include <hip/hip_runtime.h>
#include <math.h>

// UMGMQuantizer forward = two chained argmax-over-K (logit+gumbel) + codeword gather.
// Round 5: latency-chain surgery (round-4 showed VALU cut 53->30% with NO time
// change => latency-bound, not VALU-bound).
//  - Level-1 screening threshold no longer depends on c0: ||x-c0|| <= ||x|| +
//    sqrt(c2max0) (Rtab carries sqrt(c2max)). Both masks + head gumbels computed
//    up front; level-0 -> level-1 serialization now only at exact scoring.
//  - Survivor scoring software-pipelined (2 slots): survivor i+1's codeword
//    gather + c2 load issue while survivor i's fp64 butterfly runs. All
//    survivors of BOTH levels flow through one ordered pipeline (L0 then L1).
//  - um0/um1/zn wave reductions fused into one 6-round interleaved chain.
//  - u rows explicitly read twice (stream for max, L2 reload for mask) --
//    round-4's register prefetch was rematerialized by the compiler anyway;
//    explicit form keeps VGPRs < 64 for 8 waves/SIMD.
// Exact fp64 survivor scoring (butterfly order, c2, gumbel, kc tie-break) is
// unchanged -> same argmax selection as rounds 3/4.

namespace {
constexpr int Mm = 8, Kk = 2048, Dd = 128;
constexpr int MK = Mm * Kk;                    // 16384 rows per codebook
constexpr double SQRTK = 45.254833995939045;   // sqrt(2048)

__device__ __forceinline__ double wsum_d(double v) {
#pragma unroll
  for (int o = 32; o > 0; o >>= 1) v += __shfl_xor(v, o);
  return v;
}

// Exact gumbel in fp64 (matches fp64 numpy semantics: clip, log). Survivor scoring.
__device__ __forceinline__ double gumbel_d(float u) {
  double uc = fmin(fmax((double)u, 1e-6), 1.0 - 1e-6);
  return -log(-log(uc));
}

// Conservative (downward-biased) fp32 gumbel lower bound, hw-log based.
// For u->1 hw __logf(u) has poor ABSOLUTE accuracy; use exact-e series there.
// Every step biased down; total bias ~1e-4 << 0.05 margin.
__device__ __forceinline__ float gumbel_lb_f(float u) {
  float uc = fminf(fmaxf(u, 1e-6f), 1.0f - 1e-6f);
  float e = 1.0f - uc;                      // exact (Sterbenz) for uc >= 0.5
  float t;                                  // upper bound of -log(uc)
  if (e > 0.04f) {
    t = -__logf(uc);
  } else {
    // -log(1-e) = e + e^2/2 + e^3/3 + e^4/4 (+ <6e-7 rel trunc at e=0.04)
    t = e * (1.0f + e * (0.5f + e * (0.3333334f + e * 0.25f)));
  }
  t *= 1.000004f;                           // round t up -> gumbel down (safe)
  return -__logf(t) - 2e-5f;                // bias down past hw-log error
}

// prep1: squared row norms of both codebooks (fp64). One wave per row.
__global__ __launch_bounds__(256) void prep1(
    const float* __restrict__ cb0, const float* __restrict__ cb1,
    double* __restrict__ c2d0, double* __restrict__ c2d1) {
  int wid = threadIdx.x >> 6, lane = threadIdx.x & 63;
  int row = blockIdx.x * 4 + wid;              // 0..32767
  int lvl = row >= MK;
  int r = row & (MK - 1);
  const float* cb = lvl ? cb1 : cb0;
  float2 c = ((const float2*)(cb + (size_t)r * Dd))[lane];
  double s = wsum_d((double)c.x * (double)c.x + (double)c.y * (double)c.y);
  if (lane == 0) { if (lvl) c2d1[r] = s; else c2d0[r] = s; }
}

// prep2: per (level,m): Rtab = {w*(c2max-c2min), 4*w*sqrt(c2max), sqrt(c2max), 0}.
__global__ __launch_bounds__(256) void prep2(
    const double* __restrict__ c2d0, const double* __restrict__ c2d1,
    const float* __restrict__ t0, const float* __restrict__ t1,
    float4* __restrict__ Rtab) {
  int b = blockIdx.x;                          // 0..15
  int lvl = b >> 3, m = b & 7;
  const double* c2 = (lvl ? c2d1 : c2d0) + m * Kk;
  int tid = threadIdx.x;
  double mx = -1e300, mn = 1e300;
  for (int i = tid; i < Kk; i += 256) { double v = c2[i]; mx = fmax(mx, v); mn = fmin(mn, v); }
#pragma unroll
  for (int o = 32; o > 0; o >>= 1) {
    mx = fmax(mx, __shfl_xor(mx, o));
    mn = fmin(mn, __shfl_xor(mn, o));
  }
  __shared__ double smx[4], smn[4];
  int wid = tid >> 6, lane = tid & 63;
  if (lane == 0) { smx[wid] = mx; smn[wid] = mn; }
  __syncthreads();
  if (tid == 0) {
    mx = fmax(fmax(smx[0], smx[1]), fmax(smx[2], smx[3]));
    mn = fmin(fmin(smn[0], smn[1]), fmin(smn[2], smn[3]));
    double w = (double)fmaxf(lvl ? t1[m] : t0[m], 1e-6f) / SQRTK;
    float4 r;
    r.x = (float)(w * (mx - mn) * 1.0001);
    r.y = (float)(4.0 * w * sqrt(mx) * 1.0001);
    r.z = (float)(sqrt(mx) * 1.0001);
    r.w = 0.f;
    Rtab[b] = r;
  }
}

__global__ __launch_bounds__(256) void fused_kernel(
    const float* __restrict__ x,
    const float* __restrict__ cb0, const float* __restrict__ cb1,
    const float* __restrict__ t0, const float* __restrict__ t1,
    const float* __restrict__ u0, const float* __restrict__ u1,
    const double* __restrict__ c2d0, const double* __restrict__ c2d1,
    const float4* __restrict__ Rtab,
    float* __restrict__ out) {
  const int wid = threadIdx.x >> 6, lane = threadIdx.x & 63;
  const int p = blockIdx.x * 4 + wid;   // 0..32767, m-major: c2d row stays L2-hot
  const int m = p >> 12;
  const int n = p & 4095;

  const float* u0row = u0 + ((size_t)n * Mm + m) * Kk;
  const float* u1row = u1 + ((size_t)n * Mm + m) * Kk;
  const float4* a4 = (const float4*)u0row;
  const float4* b4 = (const float4*)u1row;

  // ---- PASS 1: stream both u rows, per-lane max only (values not kept live).
  float um0 = 0.f, um1 = 0.f;
#pragma unroll
  for (int j = 0; j < 8; ++j) {
    float4 a = a4[j * 64 + lane];
    float4 b = b4[j * 64 + lane];
    um0 = fmaxf(um0, fmaxf(fmaxf(a.x, a.y), fmaxf(a.z, a.w)));
    um1 = fmaxf(um1, fmaxf(fmaxf(b.x, b.y), fmaxf(b.z, b.w)));
  }
  float2 z = ((const float2*)(x + (size_t)n * 1024 + m * Dd))[lane];
  float ss = z.x * z.x + z.y * z.y;
  // Fused wave reductions: 3 streams, one 6-round chain.
#pragma unroll
  for (int o = 32; o > 0; o >>= 1) {
    um0 = fmaxf(um0, __shfl_xor(um0, o));
    um1 = fmaxf(um1, __shfl_xor(um1, o));
    ss += __shfl_xor(ss, o);
  }
  float zn = sqrtf(ss);

  const float4 R0 = Rtab[m], R1 = Rtab[8 + m];
  float thr0 = gumbel_lb_f(um0) - (R0.x + R0.y * zn) - 0.05f;
  float uthr0 = __expf(-__expf(-thr0) * 1.000004f) * (1.0f - 4e-6f);
  // Level-1 screening BEFORE c0 is known: ||x - c0|| <= zn + sqrt(c2max0).
  float zn1ub = zn + R0.z;
  float thr1 = gumbel_lb_f(um1) - (R1.x + R1.y * zn1ub) - 0.05f;
  float uthr1 = __expf(-__expf(-thr1) * 1.000004f) * (1.0f - 4e-6f);

  // ---- PASS 2: reload rows (L2-hot), build candidate masks for BOTH levels.
  unsigned mask0 = 0, mask1 = 0;
#pragma unroll
  for (int j = 0; j < 8; ++j) {
    float4 a = a4[j * 64 + lane];
    float4 b = b4[j * 64 + lane];
    mask0 |= (a.x >= uthr0 ? 1u : 0u) << (j * 4 + 0);
    mask0 |= (a.y >= uthr0 ? 1u : 0u) << (j * 4 + 1);
    mask0 |= (a.z >= uthr0 ? 1u : 0u) << (j * 4 + 2);
    mask0 |= (a.w >= uthr0 ? 1u : 0u) << (j * 4 + 3);
    mask1 |= (b.x >= uthr1 ? 1u : 0u) << (j * 4 + 0);
    mask1 |= (b.y >= uthr1 ? 1u : 0u) << (j * 4 + 1);
    mask1 |= (b.z >= uthr1 ? 1u : 0u) << (j * 4 + 2);
    mask1 |= (b.w >= uthr1 ? 1u : 0u) << (j * 4 + 3);
  }

  const double wd0 = (double)fmaxf(t0[m], 1e-6f) / SQRTK;
  const double wd1 = (double)fmaxf(t1[m], 1e-6f) / SQRTK;
  const float* cb0m = cb0 + (size_t)m * Kk * Dd;
  const float* cb1m = cb1 + (size_t)m * Kk * Dd;
  const double* c2m0 = c2d0 + m * Kk;
  const double* c2m1 = c2d1 + m * Kk;

  // ---- Head gumbels for both levels: one parallel fp64 pass across lanes.
  int hk0 = 0, hk1 = 0;
  double hg0 = 0.0, hg1 = 0.0;
  if (mask0) {
    int t = __builtin_ffs((int)mask0) - 1;
    hk0 = ((t >> 2) << 8) + (lane << 2) + (t & 3);
    hg0 = gumbel_d(u0row[hk0]);
  }
  if (mask1) {
    int t = __builtin_ffs((int)mask1) - 1;
    hk1 = ((t >> 2) << 8) + (lane << 2) + (t & 3);
    hg1 = gumbel_d(u1row[hk1]);
  }

  // Pop lowest-lane pending survivor; owner lane advances its head (rare 2nd
  // bit recomputes gumbel divergently, hidden until the next shfl).
  auto pop0 = [&](int& okc, double& og) -> bool {
    unsigned long long actv = __ballot(mask0 != 0);
    if (!actv) return false;
    int l = (int)__ffsll(actv) - 1;
    okc = __shfl(hk0, l);
    og = __shfl(hg0, l);
    if (lane == l) {
      mask0 &= mask0 - 1;
      if (mask0) {
        int t = __builtin_ffs((int)mask0) - 1;
        hk0 = ((t >> 2) << 8) + (lane << 2) + (t & 3);
        hg0 = gumbel_d(u0row[hk0]);
      }
    }
    return true;
  };
  auto pop1 = [&](int& okc, double& og) -> bool {
    unsigned long long actv = __ballot(mask1 != 0);
    if (!actv) return false;
    int l = (int)__ffsll(actv) - 1;
    okc = __shfl(hk1, l);
    og = __shfl(hg1, l);
    if (lane == l) {
      mask1 &= mask1 - 1;
      if (mask1) {
        int t = __builtin_ffs((int)mask1) - 1;
        hk1 = ((t >> 2) << 8) + (lane << 2) + (t & 3);
        hg1 = gumbel_d(u1row[hk1]);
      }
    }
    return true;
  };
  // Fill a slot: pop next survivor (all L0 first, then L1) and ISSUE its
  // codeword gather + c2 load. Returns level or -1.
  auto fill = [&](int& okc, double& og, float2& oc, double& oc2) -> int {
    int kcl; double gl;
    if (pop0(kcl, gl)) {
      oc = ((const float2*)(cb0m + (size_t)kcl * Dd))[lane];
      oc2 = c2m0[kcl];
      okc = kcl; og = gl;
      return 0;
    }
    if (pop1(kcl, gl)) {
      oc = ((const float2*)(cb1m + (size_t)kcl * Dd))[lane];
      oc2 = c2m1[kcl];
      okc = kcl; og = gl;
      return 1;
    }
    return -1;
  };

  // ---- 2-slot pipelined exact scoring (fp64, unchanged semantics).
  int Akc = 0, Bkc = 0;
  double Ag = 0.0, Bg = 0.0, Ac2 = 0.0, Bc2 = 0.0;
  float2 Ac = make_float2(0.f, 0.f), Bc = make_float2(0.f, 0.f);
  int Alvl = fill(Akc, Ag, Ac, Ac2);
  int Blvl = (Alvl >= 0) ? fill(Bkc, Bg, Bc, Bc2) : -1;

  double best0 = -1e300, best1 = -1e300;
  int bk0 = 0, bk1 = 0;
  float2 bc0 = make_float2(0.f, 0.f), bc1 = make_float2(0.f, 0.f);
  float z1x = 0.f, z1y = 0.f;
  bool z1rdy = false;

  while (Alvl >= 0) {
    if (Alvl == 0) {
      double dot = wsum_d((double)z.x * (double)Ac.x + (double)z.y * (double)Ac.y);
      double sc = (2.0 * dot - Ac2) * wd0 + Ag;   // x2 const dropped
      if (sc > best0 || (sc == best0 && Akc < bk0)) { best0 = sc; bk0 = Akc; bc0 = Ac; }
    } else {
      // All L0 entries precede any L1 entry => bc0 is final here.
      if (!z1rdy) { z1x = z.x - bc0.x; z1y = z.y - bc0.y; z1rdy = true; }
      double dot = wsum_d((double)z1x * (double)Ac.x + (double)z1y * (double)Ac.y);
      double sc = (2.0 * dot - Ac2) * wd1 + Ag;
      if (sc > best1 || (sc == best1 && Akc < bk1)) { best1 = sc; bk1 = Akc; bc1 = Ac; }
    }
    // Rotate B -> A, refill B (issues next gather under this score's butterfly).
    Alvl = Blvl; Akc = Bkc; Ag = Bg; Ac = Bc; Ac2 = Bc2;
    Blvl = (Alvl >= 0) ? fill(Bkc, Bg, Bc, Bc2) : -1;
  }

  ((float2*)(out + (size_t)n * 1024 + m * Dd))[lane] =
      make_float2(bc0.x + bc1.x, bc0.y + bc1.y);
}
}  // namespace

extern "C" void kernel_launch(void* const* d_in, const int* in_sizes, int n_in,
                              void* d_out, int out_size, void* d_ws, size_t ws_size,
                              hipStream_t stream) {
  const float* x   = (const float*)d_in[0];
  const float* cb0 = (const float*)d_in[1];
  const float* cb1 = (const float*)d_in[2];
  const float* t0  = (const float*)d_in[3];
  const float* t1  = (const float*)d_in[4];
  const float* u0  = (const float*)d_in[5];
  const float* u1  = (const float*)d_in[6];
  float* out = (float*)d_out;

  // ws: c2d0/c2d1 (16384 doubles each) + Rtab (16 float4) = 256 KB + 256 B
  char* ws = (char*)d_ws;
  double* c2d0 = (double*)ws;
  double* c2d1 = c2d0 + MK;
  float4* Rtab = (float4*)(c2d1 + MK);

  prep1<<<8192, 256, 0, stream>>>(cb0, cb1, c2d0, c2d1);
  prep2<<<16, 256, 0, stream>>>(c2d0, c2d1, t0, t1, Rtab);
  fused_kernel<<<8192, 256, 0, stream>>>(x, cb0, cb1, t0, t1, u0, u1,
                                         c2d0, c2d1, Rtab, out);
}